// Round 1
// baseline (90.536 us; speedup 1.0000x reference)
//
#include <hip/hip_runtime.h>

#define BATCH   32
#define SEQ     2048
#define MDIM    128
#define LBAS    64
#define NW      2041        // SEQ - RANK + 1
#define TW      16          // windows per tile (one tile per block)
#define NBLK    4096        // 32 batches x 128 tiles
#define APAD    136         // bf16 elems per sA row

typedef __attribute__((ext_vector_type(8))) short  short8;
typedef __attribute__((ext_vector_type(4))) float  float4v;

__device__ __forceinline__ unsigned short f2bf(float f) {
    unsigned int u = __float_as_uint(f);
    return (unsigned short)((u + 0x7FFFu + ((u >> 16) & 1u)) >> 16);
}
__device__ __forceinline__ void store_bf16x4(unsigned short* p, float4v a) {
    unsigned int lo = (unsigned)f2bf(a.x) | ((unsigned)f2bf(a.y) << 16);
    unsigned int hi = (unsigned)f2bf(a.z) | ((unsigned)f2bf(a.w) << 16);
    *reinterpret_cast<unsigned long long*>(p) = ((unsigned long long)hi << 32) | lo;
}

// ---------------------------------------------------------------------------
// Prep: M -> bf16 B-fragment-linear Mb[(k>>3)*128+n][j];
//       nkT[n][k] = Acoeff[n][k] * Bbasis[k][n]   (TRANSPOSED: main loads f4)
// ---------------------------------------------------------------------------
__global__ __launch_bounds__(256)
void ndd_prep(const float* __restrict__ Mmat,
              const float* __restrict__ Acoeff,
              const float* __restrict__ Bbasis,
              unsigned short* __restrict__ Mb,
              float* __restrict__ nkT)
{
    const int gid = blockIdx.x * 256 + threadIdx.x;
    if (gid < 2048) {                    // 128 rows x 16 k-chunks
        const int n = gid >> 4;
        const int c = gid & 15;
        const float* src = Mmat + n * MDIM + c * 8;
        short8 v;
        #pragma unroll
        for (int j = 0; j < 8; ++j) v[j] = (short)f2bf(src[j]);
        *reinterpret_cast<short8*>(Mb + ((size_t)(c * MDIM + n)) * 8) = v;
    } else if (gid < 2048 + 8192) {      // nkT: [128][64]
        const int e = gid - 2048;
        const int n = e >> 6;
        const int k = e & 63;
        nkT[e] = Acoeff[e] * Bbasis[k * MDIM + n];   // Acoeff is [n][k] too
    }
}

// ---------------------------------------------------------------------------
// Main, de-persisted: one 16-window tile per block, 4096 blocks.
// Rationale (R8): previous persistent 512-block/8-tile version ran ~34 us vs
// an ~8 us fetch roofline -- latency-bound at 8 waves/CU with barrier-
// serialized tiles. Single-tile blocks need only 16.6 KB LDS ->
// __launch_bounds__(256,4) = 4 blocks/CU = 16 waves/CU, and ~48 KB of
// global_load_lds DMA in flight per CU from pure block TLP. No manual
// vmcnt/s_barrier pipelining needed; plain __syncthreads().
// Per-element arithmetic identical to the proven R7 kernel.
// ---------------------------------------------------------------------------
__global__ __launch_bounds__(256, 4)
void ndd_main(const float* __restrict__ x,            // [32][2048][128]
              const unsigned short* __restrict__ Mb,  // bf16 frag-linear
              const float* __restrict__ nkT,          // [128][64]
              float* __restrict__ partial)            // [NBLK]
{
    __shared__ __align__(16) float sRaw[12 * 256];            // 12 KB (24 rows)
    __shared__ __align__(16) unsigned short sA[TW * APAD];    // 4.25 KB
    __shared__ float sred[4];

    const int tid  = threadIdx.x;
    const int lane = tid & 63;
    const int wave = tid >> 6;

    // XCD-aware swizzle: launch id L -> work id w so that 512 consecutive
    // work tiles share one XCD's L2 (adjacent tiles overlap by 8 rows).
    const int w0   = (blockIdx.x & 7) * (NBLK / 8) + (blockIdx.x >> 3);
    const int b    = w0 >> 7;                  // batch
    const int t    = w0 & 127;                 // tile within batch
    const int base = t * TW;                   // first window of tile
    const float* xb = x + (size_t)b * SEQ * MDIM;

    // ---- DMA first: 12 chunks (24 rows x 128 floats), 3 chunks per wave ----
    #pragma unroll
    for (int i = 0; i < 3; ++i) {
        const int c = wave * 3 + i;            // chunk 0..11
        int r0 = base + 2 * c;
        r0 = r0 > 2046 ? 2046 : r0;            // stay in-bounds (tail tiles)
        const float* g = xb + (size_t)r0 * MDIM + lane * 4;
        __builtin_amdgcn_global_load_lds(
            (const __attribute__((address_space(1))) void*)g,
            (__attribute__((address_space(3))) void*)&sRaw[c * 256],
            16, 0, 0);
    }

    const int l15 = lane & 15;
    const int q   = lane >> 4;
    const int nb  = wave * 32;                 // this wave's n-columns

    // ---- hoist B-fragments (L2-resident, 8 frags = 32 VGPRs) ----
    short8 bfr[4][2];
    #pragma unroll
    for (int kk = 0; kk < 4; ++kk)
        #pragma unroll
        for (int nj = 0; nj < 2; ++nj)
            bfr[kk][nj] = *reinterpret_cast<const short8*>(
                Mb + ((size_t)((kk * 4 + q) * MDIM + nb + nj * 16 + l15)) * 8);

    // ---- nk: window w = base + q*4 + r, kmod = w % 64 = (t&3)*16 + q*4 + r ----
    const int p = t & 3;
    float4v nkreg[2];
    #pragma unroll
    for (int nj = 0; nj < 2; ++nj)
        nkreg[nj] = *reinterpret_cast<const float4v*>(
            nkT + (size_t)(nb + nj * 16 + l15) * LBAS + p * 16 + q * 4);

    __syncthreads();   // drains vmcnt(0): sRaw + hoists complete

    // ---- phase 2: window means from sRaw -> bf16 sA (identical fp tree) ----
    {
        const int m4 = tid & 31;
        const int wg = tid >> 5;               // windows wg*2, wg*2+1
        const float4v* R = reinterpret_cast<const float4v*>(&sRaw[0]);
        float4v rows[9];
        #pragma unroll
        for (int i = 0; i < 9; ++i) rows[i] = R[(wg * 2 + i) * 32 + m4];
        float4v acc = ((rows[0] + rows[1]) + (rows[2] + rows[3])) +
                      ((rows[4] + rows[5]) + (rows[6] + rows[7]));
        store_bf16x4(&sA[(wg * 2) * APAD + m4 * 4], acc * 0.125f);
        acc += rows[8] - rows[0];
        store_bf16x4(&sA[(wg * 2 + 1) * APAD + m4 * 4], acc * 0.125f);
    }

    __syncthreads();

    // ---- phase 3: MFMA C[w][n], pure LDS + registers ----
    float4v accf[2] = {(float4v){0.f,0.f,0.f,0.f}, (float4v){0.f,0.f,0.f,0.f}};
    #pragma unroll
    for (int kk = 0; kk < 4; ++kk) {
        const short8 af = *reinterpret_cast<const short8*>(
            &sA[l15 * APAD + kk * 32 + q * 8]);
        #pragma unroll
        for (int nj = 0; nj < 2; ++nj)
            accf[nj] = __builtin_amdgcn_mfma_f32_16x16x32_bf16(
                af, bfr[kk][nj], accf[nj], 0, 0, 0);
    }

    // ---- epilogue: (C - nk)^2, masked ----
    float local = 0.f;
    #pragma unroll
    for (int nj = 0; nj < 2; ++nj) {
        #pragma unroll
        for (int r = 0; r < 4; ++r) {
            const int w = base + q * 4 + r;
            if (w < NW) {
                const float d = accf[nj][r] - nkreg[nj][r];
                local += d * d;
            }
        }
    }

    // ---- block reduce -> one partial ----
    #pragma unroll
    for (int off = 32; off > 0; off >>= 1)
        local += __shfl_down(local, off, 64);
    if (lane == 0) sred[wave] = local;
    __syncthreads();
    if (tid == 0)
        partial[blockIdx.x] = (sred[0] + sred[1]) + (sred[2] + sred[3]);
}

// ---------------------------------------------------------------------------
// Final reduce: NBLK partials -> scalar D
// ---------------------------------------------------------------------------
__global__ __launch_bounds__(256)
void ndd_reduce(const float* __restrict__ partial, float* __restrict__ out)
{
    __shared__ float sred[4];
    float s = 0.f;
    #pragma unroll
    for (int i = 0; i < NBLK / 256; ++i)
        s += partial[threadIdx.x + i * 256];
    #pragma unroll
    for (int off = 32; off > 0; off >>= 1) s += __shfl_down(s, off, 64);
    if ((threadIdx.x & 63) == 0) sred[threadIdx.x >> 6] = s;
    __syncthreads();
    if (threadIdx.x == 0)
        out[0] = ((sred[0] + sred[1]) + (sred[2] + sred[3])) * (1.0f / 8359936.0f);
}

extern "C" void kernel_launch(void* const* d_in, const int* in_sizes, int n_in,
                              void* d_out, int out_size, void* d_ws, size_t ws_size,
                              hipStream_t stream) {
    const float* x     = (const float*)d_in[0];
    const float* Mmat  = (const float*)d_in[1];
    const float* Acoef = (const float*)d_in[2];
    const float* Bbas  = (const float*)d_in[3];
    float* out         = (float*)d_out;

    unsigned short* Mb = (unsigned short*)d_ws;             // 32 KB bf16
    float* nkTp        = (float*)((char*)d_ws + 32768);     // 32 KB fp32
    float* part        = (float*)((char*)d_ws + 65536);     // 16 KB partials

    ndd_prep<<<40, 256, 0, stream>>>(Mmat, Acoef, Bbas, Mb, nkTp);
    ndd_main<<<NBLK, 256, 0, stream>>>(x, Mb, nkTp, part);
    ndd_reduce<<<1, 256, 0, stream>>>(part, out);
}

// Round 2
// 86.317 us; speedup vs baseline: 1.0489x; 1.0489x over previous
//
#include <hip/hip_runtime.h>

#define BATCH   32
#define SEQ     2048
#define MDIM    128
#define LBAS    64
#define NW      2041        // SEQ - RANK + 1
#define TW      16          // windows per tile
#define NTILE   4           // tiles per block -> 64 windows/block
#define NBLK    1024        // 32 batches x 32 tile-groups
#define APAD    136         // bf16 elems per sA row

typedef __attribute__((ext_vector_type(8))) short  short8;
typedef __attribute__((ext_vector_type(4))) float  float4v;

__device__ __forceinline__ unsigned short f2bf(float f) {
    unsigned int u = __float_as_uint(f);
    return (unsigned short)((u + 0x7FFFu + ((u >> 16) & 1u)) >> 16);
}
__device__ __forceinline__ void store_bf16x4(unsigned short* p, float4v a) {
    unsigned int lo = (unsigned)f2bf(a.x) | ((unsigned)f2bf(a.y) << 16);
    unsigned int hi = (unsigned)f2bf(a.z) | ((unsigned)f2bf(a.w) << 16);
    *reinterpret_cast<unsigned long long*>(p) = ((unsigned long long)hi << 32) | lo;
}

// ---------------------------------------------------------------------------
// Prep: M -> bf16 B-fragment-linear Mb[(k>>3)*128+n][j];
//       nkT[n][k] = Acoeff[n][k] * Bbasis[k][n]   (TRANSPOSED: main loads f4)
// ---------------------------------------------------------------------------
__global__ __launch_bounds__(256)
void ndd_prep(const float* __restrict__ Mmat,
              const float* __restrict__ Acoeff,
              const float* __restrict__ Bbasis,
              unsigned short* __restrict__ Mb,
              float* __restrict__ nkT)
{
    const int gid = blockIdx.x * 256 + threadIdx.x;
    if (gid < 2048) {                    // 128 rows x 16 k-chunks
        const int n = gid >> 4;
        const int c = gid & 15;
        const float* src = Mmat + n * MDIM + c * 8;
        short8 v;
        #pragma unroll
        for (int j = 0; j < 8; ++j) v[j] = (short)f2bf(src[j]);
        *reinterpret_cast<short8*>(Mb + ((size_t)(c * MDIM + n)) * 8) = v;
    } else if (gid < 2048 + 8192) {      // nkT: [128][64]
        const int e = gid - 2048;
        const int n = e >> 6;
        const int k = e & 63;
        nkT[e] = Acoeff[e] * Bbasis[k * MDIM + n];   // Acoeff is [n][k] too
    }
}

// ---------------------------------------------------------------------------
// Main (R9): R7-proven persistent pipeline, occupancy-tuned.
// R8 post-mortem: de-persist (4096 blocks, (256,4)=128-VGPR cap, no intra-
// block pipeline) regressed 82.8->90.5 us. Revert to persistent structure.
// R9 delta vs R7: 512 blocks x 8 tiles -> 1024 blocks x 4 tiles. LDS stays
// 40.3 KB (3 raw buffers), which permits 3 blocks/CU -- but R7 only ever had
// 2 resident (512 blocks = 2/CU exactly) and (256,2) allowed >170 VGPR.
// __launch_bounds__(256,3) caps VGPR at ~170 so the 3rd block is schedulable,
// and phase-2 is re-expressed with the IDENTICAL FP tree but sliding liveness
// (~20 live regs vs 36) so 170 is met without spills.
// Pipeline (unchanged): 3-buffer raw staging, depth-2 global_load_lds
// prefetch, raw s_barrier + manual per-wave vmcnt(3): 6 chunks/wave in
// flight in steady state.
// ---------------------------------------------------------------------------
__global__ __launch_bounds__(256, 3)
void ndd_main(const float* __restrict__ x,            // [32][2048][128]
              const unsigned short* __restrict__ Mb,  // bf16 frag-linear
              const float* __restrict__ nkT,          // [128][64]
              float* __restrict__ partial)            // [NBLK]
{
    __shared__ __align__(16) float sRaw[3][12 * 256];             // 3 x 12 KB
    __shared__ __align__(16) unsigned short sA[TW * APAD];        // 4.25 KB
    __shared__ float sred[4];

    const int tid  = threadIdx.x;
    const int lane = tid & 63;
    const int wave = tid >> 6;
    const int b    = blockIdx.x >> 5;          // batch (32 groups per batch)
    const int base = (blockIdx.x & 31) * 64;   // window base (mult of 64)
    const float* xb = x + (size_t)b * SEQ * MDIM;

    const int l15 = lane & 15;
    const int q   = lane >> 4;
    const int nb  = wave * 32;                 // this wave's n-columns

    // ---- hoist B-fragments (tile-invariant): 8 frags = 32 VGPRs ----
    short8 bfr[4][2];
    #pragma unroll
    for (int kk = 0; kk < 4; ++kk)
        #pragma unroll
        for (int nj = 0; nj < 2; ++nj)
            bfr[kk][nj] = *reinterpret_cast<const short8*>(
                Mb + ((size_t)((kk * 4 + q) * MDIM + nb + nj * 16 + l15)) * 8);

    // ---- hoist nk via nkT: k = p*16 + q*4 + r -> one float4 per (p,nj) ----
    // base is a multiple of 64 so kmod(w) = j*16 + q*4 + r, i.e. p = j.
    float4v nkreg[4][2];
    #pragma unroll
    for (int p = 0; p < 4; ++p)
        #pragma unroll
        for (int nj = 0; nj < 2; ++nj)
            nkreg[p][nj] = *reinterpret_cast<const float4v*>(
                nkT + (size_t)(nb + nj * 16 + l15) * LBAS + p * 16 + q * 4);

    // ---- DMA: 12 chunks (24 rows) per tile, 3 chunks per wave ----
    auto issue = [&](int j) {
        const int W0r = base + j * TW;
        #pragma unroll
        for (int i = 0; i < 3; ++i) {
            const int c = wave * 3 + i;            // chunk 0..11
            int r0 = W0r + 2 * c;
            r0 = r0 > 2046 ? 2046 : r0;            // real rows only
            const float* g = xb + (size_t)r0 * MDIM + lane * 4;
            __builtin_amdgcn_global_load_lds(
                (const __attribute__((address_space(1))) void*)g,
                (__attribute__((address_space(3))) void*)&sRaw[j % 3][c * 256],
                16, 0, 0);
        }
    };
    issue(0);
    issue(1);

    float local = 0.f;

    #pragma unroll
    for (int j = 0; j < NTILE; ++j) {
        // wait: tile j's 3 chunks done (tile j+1's 3 may still fly)
        __builtin_amdgcn_sched_barrier(0);
        if (j == NTILE - 1) __builtin_amdgcn_s_waitcnt(0x0F70);  // vmcnt(0)
        else                __builtin_amdgcn_s_waitcnt(0x0F73);  // vmcnt(3)
        asm volatile("s_barrier" ::: "memory");
        __builtin_amdgcn_sched_barrier(0);

        // ---- phase 2: window means from raw[j%3] -> bf16 sA ----
        // Identical FP tree to R7: ((r0+r1)+(r2+r3))+((r4+r5)+(r6+r7)),
        // second window acc + r8 - r0 -- expressed with sliding liveness
        // (~5 live float4 instead of 9) for the 170-VGPR budget.
        {
            const int m4 = tid & 31;
            const int wg = tid >> 5;               // windows wg*2, wg*2+1
            const float4v* R = reinterpret_cast<const float4v*>(&sRaw[j % 3][0]);
            const float4v* Rb = R + (wg * 2) * 32 + m4;
            float4v r0  = Rb[0];
            float4v t0  = r0 + Rb[32];
            float4v t1  = Rb[64] + Rb[96];
            float4v u0  = t0 + t1;
            float4v t2  = Rb[128] + Rb[160];
            float4v t3  = Rb[192] + Rb[224];
            float4v acc = u0 + (t2 + t3);
            store_bf16x4(&sA[(wg * 2) * APAD + m4 * 4], acc * 0.125f);
            acc += Rb[256] - r0;
            store_bf16x4(&sA[(wg * 2 + 1) * APAD + m4 * 4], acc * 0.125f);
        }

        __builtin_amdgcn_sched_barrier(0);
        __builtin_amdgcn_s_waitcnt(0xC07F);        // lgkmcnt(0) only
        asm volatile("s_barrier" ::: "memory");
        __builtin_amdgcn_sched_barrier(0);

        // ---- depth-2 prefetch: tile j+2 into buffer (j+2)%3 ----
        if (j + 2 < NTILE) issue(j + 2);

        // ---- phase 3: MFMA C[w][n], pure LDS + registers ----
        float4v accf[2] = {(float4v){0.f,0.f,0.f,0.f}, (float4v){0.f,0.f,0.f,0.f}};
        #pragma unroll
        for (int kk = 0; kk < 4; ++kk) {
            const short8 af = *reinterpret_cast<const short8*>(
                &sA[l15 * APAD + kk * 32 + q * 8]);
            #pragma unroll
            for (int nj = 0; nj < 2; ++nj)
                accf[nj] = __builtin_amdgcn_mfma_f32_16x16x32_bf16(
                    af, bfr[kk][nj], accf[nj], 0, 0, 0);
        }

        // ---- epilogue: (C - nk)^2, masked ----
        const int p = j & 3;                       // == j for NTILE=4
        #pragma unroll
        for (int nj = 0; nj < 2; ++nj) {
            #pragma unroll
            for (int r = 0; r < 4; ++r) {
                const int w = base + j * TW + q * 4 + r;
                if (w < NW) {
                    const float d = accf[nj][r] - nkreg[p][nj][r];
                    local += d * d;
                }
            }
        }
    }

    // ---- block reduce -> one partial ----
    #pragma unroll
    for (int off = 32; off > 0; off >>= 1)
        local += __shfl_down(local, off, 64);
    if (lane == 0) sred[wave] = local;
    __syncthreads();
    if (tid == 0)
        partial[blockIdx.x] = (sred[0] + sred[1]) + (sred[2] + sred[3]);
}

// ---------------------------------------------------------------------------
// Final reduce: NBLK partials -> scalar D
// ---------------------------------------------------------------------------
__global__ __launch_bounds__(256)
void ndd_reduce(const float* __restrict__ partial, float* __restrict__ out)
{
    __shared__ float sred[4];
    float s = 0.f;
    #pragma unroll
    for (int i = 0; i < NBLK / 256; ++i)
        s += partial[threadIdx.x + i * 256];
    #pragma unroll
    for (int off = 32; off > 0; off >>= 1) s += __shfl_down(s, off, 64);
    if ((threadIdx.x & 63) == 0) sred[threadIdx.x >> 6] = s;
    __syncthreads();
    if (threadIdx.x == 0)
        out[0] = ((sred[0] + sred[1]) + (sred[2] + sred[3])) * (1.0f / 8359936.0f);
}

extern "C" void kernel_launch(void* const* d_in, const int* in_sizes, int n_in,
                              void* d_out, int out_size, void* d_ws, size_t ws_size,
                              hipStream_t stream) {
    const float* x     = (const float*)d_in[0];
    const float* Mmat  = (const float*)d_in[1];
    const float* Acoef = (const float*)d_in[2];
    const float* Bbas  = (const float*)d_in[3];
    float* out         = (float*)d_out;

    unsigned short* Mb = (unsigned short*)d_ws;             // 32 KB bf16
    float* nkTp        = (float*)((char*)d_ws + 32768);     // 32 KB fp32
    float* part        = (float*)((char*)d_ws + 65536);     // 4 KB partials

    ndd_prep<<<40, 256, 0, stream>>>(Mmat, Acoef, Bbas, Mb, nkTp);
    ndd_main<<<NBLK, 256, 0, stream>>>(x, Mb, nkTp, part);
    ndd_reduce<<<1, 256, 0, stream>>>(part, out);
}